// Round 1
// baseline (113.745 us; speedup 1.0000x reference)
//
#include <hip/hip_runtime.h>

// Masked scatter-add: out[index[i]] += rate[i] where starttime[i] <= t < endtime[i].
// Memory-bound: 4 arrays x 10M x 4B = 160 MB streamed. ~5% of events active ->
// ~500K global atomics over 2000 bins; direct predicated atomicAdd is cheapest.

__global__ void __launch_bounds__(256)
inpatient_input_kernel(const int* __restrict__ index,
                       const float* __restrict__ rate,
                       const float* __restrict__ starttime,
                       const float* __restrict__ endtime,
                       const float* __restrict__ t_ptr,
                       float* __restrict__ out,
                       int n)
{
    const float t = t_ptr[0];
    const int tid      = blockIdx.x * blockDim.x + threadIdx.x;
    const int nthreads = gridDim.x * blockDim.x;

    const int nvec = n >> 2;  // number of 4-element chunks

    const int4*   idx4v = reinterpret_cast<const int4*>(index);
    const float4* rat4v = reinterpret_cast<const float4*>(rate);
    const float4* st4v  = reinterpret_cast<const float4*>(starttime);
    const float4* en4v  = reinterpret_cast<const float4*>(endtime);

    for (int i = tid; i < nvec; i += nthreads) {
        const int4   i4 = idx4v[i];
        const float4 r4 = rat4v[i];
        const float4 s4 = st4v[i];
        const float4 e4 = en4v[i];

        if (s4.x <= t && t < e4.x) atomicAdd(&out[i4.x], r4.x);
        if (s4.y <= t && t < e4.y) atomicAdd(&out[i4.y], r4.y);
        if (s4.z <= t && t < e4.z) atomicAdd(&out[i4.z], r4.z);
        if (s4.w <= t && t < e4.w) atomicAdd(&out[i4.w], r4.w);
    }

    // Tail (N % 4) — N=10M is divisible by 4, but stay generic.
    for (int i = (nvec << 2) + tid; i < n; i += nthreads) {
        const float s = starttime[i];
        const float e = endtime[i];
        if (s <= t && t < e) atomicAdd(&out[index[i]], rate[i]);
    }
}

extern "C" void kernel_launch(void* const* d_in, const int* in_sizes, int n_in,
                              void* d_out, int out_size, void* d_ws, size_t ws_size,
                              hipStream_t stream)
{
    const int*   index     = (const int*)  d_in[0];
    const float* rate      = (const float*)d_in[1];
    const float* starttime = (const float*)d_in[2];
    const float* endtime   = (const float*)d_in[3];
    const float* t_ptr     = (const float*)d_in[4];
    // d_in[5] is `size` (==out_size); unused.

    float* out = (float*)d_out;
    const int n = in_sizes[0];

    // Atomics accumulate into d_out -> must zero it every call (replays are
    // not re-poisoned by the harness).
    hipMemsetAsync(out, 0, (size_t)out_size * sizeof(float), stream);

    const int block = 256;
    const int nvec  = n >> 2;
    int grid = (nvec + block - 1) / block;
    if (grid > 2048) grid = 2048;   // 8 blocks/CU x 256 CUs; grid-stride the rest
    if (grid < 1) grid = 1;

    inpatient_input_kernel<<<grid, block, 0, stream>>>(
        index, rate, starttime, endtime, t_ptr, out, n);
}

// Round 2
// 45.254 us; speedup vs baseline: 2.5135x; 2.5135x over previous
//
#include <hip/hip_runtime.h>

// Masked scatter-add: out[index[i]] += rate[i] where starttime[i] <= t < endtime[i].
//
// R1 lesson: 500K device-scope atomicAdds over 2000 addresses serialize at the
// memory-side coherence point (WRITE_SIZE showed ~16 MB = 500K x 32B atomic
// write-backs; 250-way per-address contention; 113 us at 11% HBM BW).
//
// R2: per-block LDS histogram (no global atomics in the streaming loop),
// plain-store partials to d_ws, then a small column-sum reduce kernel.

#define MAX_BINS 2048   // problem SIZE = 2000; static LDS must be compile-time

__global__ void __launch_bounds__(256)
hist_partial_kernel(const int* __restrict__ index,
                    const float* __restrict__ rate,
                    const float* __restrict__ starttime,
                    const float* __restrict__ endtime,
                    const float* __restrict__ t_ptr,
                    float* __restrict__ ws,   // [gridDim.x][size] partials
                    int n, int size)
{
    __shared__ float hist[MAX_BINS];
    for (int j = threadIdx.x; j < size; j += blockDim.x) hist[j] = 0.0f;
    __syncthreads();

    const float t = t_ptr[0];
    const int tid      = blockIdx.x * blockDim.x + threadIdx.x;
    const int nthreads = gridDim.x * blockDim.x;
    const int nvec     = n >> 2;

    const int4*   idx4v = reinterpret_cast<const int4*>(index);
    const float4* rat4v = reinterpret_cast<const float4*>(rate);
    const float4* st4v  = reinterpret_cast<const float4*>(starttime);
    const float4* en4v  = reinterpret_cast<const float4*>(endtime);

    for (int i = tid; i < nvec; i += nthreads) {
        const int4   i4 = idx4v[i];
        const float4 r4 = rat4v[i];
        const float4 s4 = st4v[i];
        const float4 e4 = en4v[i];

        if (s4.x <= t && t < e4.x) atomicAdd(&hist[i4.x], r4.x);   // ds_add_f32
        if (s4.y <= t && t < e4.y) atomicAdd(&hist[i4.y], r4.y);
        if (s4.z <= t && t < e4.z) atomicAdd(&hist[i4.z], r4.z);
        if (s4.w <= t && t < e4.w) atomicAdd(&hist[i4.w], r4.w);
    }
    // Tail (N % 4) — N=10M divisible by 4, but stay generic.
    for (int i = (nvec << 2) + tid; i < n; i += nthreads) {
        if (starttime[i] <= t && t < endtime[i]) atomicAdd(&hist[index[i]], rate[i]);
    }

    __syncthreads();
    float* part = ws + (size_t)blockIdx.x * size;
    for (int j = threadIdx.x; j < size; j += blockDim.x) part[j] = hist[j];  // coalesced
}

// out[j] += sum_b ws[b][j] over this block's y-chunk of b. Lanes read
// consecutive j at fixed b -> coalesced. 2000 x NPB atomics, ~NPB-way contention.
__global__ void __launch_bounds__(256)
reduce_partials_kernel(const float* __restrict__ ws,
                       float* __restrict__ out,
                       int npart, int size)
{
    const int j = blockIdx.x * blockDim.x + threadIdx.x;
    if (j >= size) return;

    const int chunk  = npart / gridDim.y;
    const int bstart = blockIdx.y * chunk;
    const int bend   = (blockIdx.y == gridDim.y - 1) ? npart : bstart + chunk;

    float sum = 0.0f;
    int b = bstart;
    #pragma unroll 4
    for (; b + 4 <= bend; b += 4) {
        sum += ws[(size_t)(b + 0) * size + j];
        sum += ws[(size_t)(b + 1) * size + j];
        sum += ws[(size_t)(b + 2) * size + j];
        sum += ws[(size_t)(b + 3) * size + j];
    }
    for (; b < bend; ++b) sum += ws[(size_t)b * size + j];

    atomicAdd(&out[j], sum);
}

// Fallback (ws too small / size too large): direct predicated global atomics.
__global__ void __launch_bounds__(256)
direct_atomic_kernel(const int* __restrict__ index,
                     const float* __restrict__ rate,
                     const float* __restrict__ starttime,
                     const float* __restrict__ endtime,
                     const float* __restrict__ t_ptr,
                     float* __restrict__ out, int n)
{
    const float t = t_ptr[0];
    const int tid      = blockIdx.x * blockDim.x + threadIdx.x;
    const int nthreads = gridDim.x * blockDim.x;
    for (int i = tid; i < n; i += nthreads) {
        if (starttime[i] <= t && t < endtime[i]) atomicAdd(&out[index[i]], rate[i]);
    }
}

extern "C" void kernel_launch(void* const* d_in, const int* in_sizes, int n_in,
                              void* d_out, int out_size, void* d_ws, size_t ws_size,
                              hipStream_t stream)
{
    const int*   index     = (const int*)  d_in[0];
    const float* rate      = (const float*)d_in[1];
    const float* starttime = (const float*)d_in[2];
    const float* endtime   = (const float*)d_in[3];
    const float* t_ptr     = (const float*)d_in[4];

    float* out = (float*)d_out;
    float* ws  = (float*)d_ws;
    const int n    = in_sizes[0];
    const int size = out_size;

    // Atomics/sums accumulate into d_out -> zero it every call (replays are
    // not re-poisoned by the harness).
    hipMemsetAsync(out, 0, (size_t)size * sizeof(float), stream);

    const int block = 256;

    // Partial-histogram count bounded by workspace.
    int npart = (int)(ws_size / ((size_t)size * sizeof(float)));
    if (npart > 2048) npart = 2048;
    npart &= ~7;  // multiple of 8 for clean y-chunking

    if (size <= MAX_BINS && npart >= 64) {
        hist_partial_kernel<<<npart, block, 0, stream>>>(
            index, rate, starttime, endtime, t_ptr, ws, n, size);

        dim3 g2((size + block - 1) / block, 8);
        reduce_partials_kernel<<<g2, block, 0, stream>>>(ws, out, npart, size);
    } else {
        int grid = (n + block - 1) / block;
        if (grid > 2048) grid = 2048;
        direct_atomic_kernel<<<grid, block, 0, stream>>>(
            index, rate, starttime, endtime, t_ptr, out, n);
    }
}